// Round 7
// baseline (244.823 us; speedup 1.0000x reference)
//
#include <hip/hip_runtime.h>
#include <stdint.h>

#define Mdim 4096
#define Kdim 4096
#define Ndim 4096

typedef __attribute__((ext_vector_type(4))) int v4i;
typedef __attribute__((ext_vector_type(16))) int v16i;

__device__ __forceinline__ void gload_lds16(const void* g, void* l) {
  __builtin_amdgcn_global_load_lds(
      (__attribute__((address_space(1))) void*)(uintptr_t)g,
      (__attribute__((address_space(3))) void*)(uint32_t)(uintptr_t)l,
      16, 0, 0);
}

// ---- fused pack, 512 threads ----------------------------------------------
// Blocks [0,256): y-strips. Block owns 16 n-columns x full K. Per 512-k chunk:
//   phase1: coalesced int4 loads, pack 4 n-bytes to a word, bias via
//           ^0x80808080, store LDS [512 k][5 words].
//   phase2: thread (n=t>>5, kq=t&31) gathers 16 k-bytes for its n, int4 store
//           to yt[n][k]. csy accumulated in registers across chunks -> shfl
//           reduce -> ONE plain store per n. NO atomics, NO csy memset.
// Blocks [256,2304): x rows, 2 per block (256 thr each): CONTIGUOUS int4 in
//   (src[tt*4+i] -- R6 bug was strided src[tt+256*i] with the int4 store),
//   int4 out, row sum via shfl + LDS.
__global__ __launch_bounds__(512) void pack_fused_kernel(
    const int* __restrict__ x, const int* __restrict__ y,
    char* __restrict__ x8, char* __restrict__ yt, int* __restrict__ rsx,
    int* __restrict__ csy) {
  __shared__ int shm[512 * 5];  // y: [512][5]; x: [0..7] as red
  const int t = threadIdx.x;
  if (blockIdx.x < 256) {
    const int n0 = blockIdx.x * 16;
    const int n = t >> 5;         // 0..15
    const int kq = t & 31;        // 16-k run within chunk
    const int colw = n >> 2;      // LDS word column
    const int byi = (n & 3) * 8;  // byte select
    int bsum = 0;
#pragma unroll 1
    for (int c = 0; c < 8; ++c) {
      const int k0 = c * 512;
      // phase1: 512k x 16n -> LDS packed words
#pragma unroll
      for (int p = 0; p < 4; ++p) {
        const int r = (t >> 2) + p * 128;  // k row 0..511
        int4 v = *(const int4*)(y + (size_t)(k0 + r) * Ndim + n0 + (t & 3) * 4);
        int wd = (v.x & 0xff) | ((v.y & 0xff) << 8) | ((v.z & 0xff) << 16) |
                 (v.w << 24);
        shm[r * 5 + (t & 3)] = wd ^ 0x80808080;  // == (b-128)&0xff per byte
      }
      __syncthreads();
      // phase2: transpose-gather 16 k-bytes for column n
      int outw[4];
#pragma unroll
      for (int j = 0; j < 4; ++j) {
        int b[4];
#pragma unroll
        for (int jj = 0; jj < 4; ++jj) {
          const int word = shm[(kq * 16 + j * 4 + jj) * 5 + colw];
          b[jj] = (word >> byi) & 0xff;
          bsum += (int)(char)b[jj];
        }
        outw[j] = b[0] | (b[1] << 8) | (b[2] << 16) | (b[3] << 24);
      }
      *(int4*)(yt + (size_t)(n0 + n) * Kdim + k0 + kq * 16) =
          make_int4(outw[0], outw[1], outw[2], outw[3]);
      __syncthreads();
    }
    // reduce bsum over the 32 kq-lanes sharing this n (masks stay in-group)
    bsum += __shfl_xor(bsum, 1, 64);
    bsum += __shfl_xor(bsum, 2, 64);
    bsum += __shfl_xor(bsum, 4, 64);
    bsum += __shfl_xor(bsum, 8, 64);
    bsum += __shfl_xor(bsum, 16, 64);
    if (kq == 0) csy[n0 + n] = bsum;
  } else {
    // x pack: 2 rows per block, 256 threads per row
    const int rowp = (int)(blockIdx.x - 256) * 2;
    const int h = t >> 8;    // row half
    const int tt = t & 255;
    const int row = rowp + h;
    const int4* src = (const int4*)(x + (size_t)row * Kdim);
    int4* dst = (int4*)(x8 + (size_t)row * Kdim);
    int sum = 0;
    int wd[4];
#pragma unroll
    for (int i = 0; i < 4; ++i) {
      int4 v = src[tt * 4 + i];  // contiguous 64B/lane (matches int4 store)
      sum += v.x + v.y + v.z + v.w;
      wd[i] = (v.x & 0xff) | ((v.y & 0xff) << 8) | ((v.z & 0xff) << 16) |
              (v.w << 24);
    }
    dst[tt] = make_int4(wd[0], wd[1], wd[2], wd[3]);
#pragma unroll
    for (int o = 32; o > 0; o >>= 1) sum += __shfl_down(sum, o, 64);
    if ((t & 63) == 0) shm[t >> 6] = sum;  // red[0..7]
    __syncthreads();
    if (t == 0) rsx[rowp] = shm[0] + shm[1] + shm[2] + shm[3];
    if (t == 256) rsx[rowp + 1] = shm[4] + shm[5] + shm[6] + shm[7];
  }
}

// ---- i8 GEMM: C = 7.5e-4*(A8 @ B8^T - 32*rsx[m] + 66*csy[n] - 2112*K) ------
// FROZEN (best-known R2 variant; cross-session noise band 76-91us). 512 thr /
// 8 waves, tile 256x256, BK=64, 4-phase K-tile split, 3 LDS buffers, counted
// vmcnt(4), setprio around MFMA clusters.
__global__ __launch_bounds__(512, 2) void gemm_i8_kernel(
    const char* __restrict__ A, const char* __restrict__ B,
    const int* __restrict__ rsx, const int* __restrict__ csy,
    float* __restrict__ out) {
  __shared__ __align__(16) char lds[3 * 32768];  // buf: [As 16K | Bs 16K] x3
  const int t = threadIdx.x;
  const int l = t & 63;
  const int w = t >> 6;      // 0..7
  const int warow = w >> 1;  // 0..3 (x64 rows)
  const int wbcol = w & 1;   // 0..1 (x128 cols)
  const int bm = blockIdx.y * 256;
  const int bn = blockIdx.x * 256;

  v16i acc[2][4];
#pragma unroll
  for (int i = 0; i < 2; ++i)
#pragma unroll
    for (int j = 0; j < 4; ++j)
#pragma unroll
      for (int q = 0; q < 16; ++q) acc[i][j][q] = 0;

  const int srow = t >> 2;  // 0..127
  const int cswz = ((t & 3) ^ ((t >> 3) & 3)) * 16;
  const char* gA = A + (size_t)(bm + srow) * Kdim + cswz;
  const char* gB = B + (size_t)(bn + srow) * Kdim + cswz;

#define STAGE(buf_off, koff)                                                  \
  do {                                                                        \
    _Pragma("unroll") for (int i = 0; i < 2; ++i)                             \
        gload_lds16(gA + (koff) + (size_t)i * 128 * Kdim,                     \
                    lds + (buf_off) + i * 8192 + t * 16);                     \
    _Pragma("unroll") for (int i = 0; i < 2; ++i)                             \
        gload_lds16(gB + (koff) + (size_t)i * 128 * Kdim,                     \
                    lds + (buf_off) + 16384 + i * 8192 + t * 16);             \
  } while (0)

#define STG(sbo, koff, idx)                                                   \
  gload_lds16(((idx) < 2 ? gA : gB) + (koff) + (size_t)((idx)&1) * 128 * Kdim,\
              lds + (sbo) + ((idx) < 2 ? 0 : 16384) + ((idx)&1) * 8192 +      \
                  t * 16)

  const int arow = warow * 64 + (l & 31);
  const int brow = wbcol * 128 + (l & 31);
  const int lhalf = l >> 5;
  const int lkey = (l >> 1) & 3;
  const int slot0 = ((0 + lhalf) ^ lkey) * 16;
  const int slot1 = ((2 + lhalf) ^ lkey) * 16;

#define MFMA(a, b, c) __builtin_amdgcn_mfma_i32_32x32x32_i8(a, b, c, 0, 0, 0)
#define SETP(n) __builtin_amdgcn_s_setprio(n)
#define FENCE() __builtin_amdgcn_sched_barrier(0)
#define BAR()                                                                 \
  do {                                                                        \
    asm volatile("" ::: "memory");                                            \
    __builtin_amdgcn_s_barrier();                                             \
    asm volatile("" ::: "memory");                                            \
  } while (0)
#define WAITV(n) asm volatile("s_waitcnt vmcnt(" #n ")" ::: "memory")

#define TILE(bo, sbo, skoff, dostage, TAILWAIT)                               \
  do {                                                                        \
    const char* As = lds + (bo);                                              \
    const char* Bs = lds + (bo) + 16384;                                      \
    v4i a0, a1, b0, b1;                                                       \
    a0 = *(const v4i*)(As + arow * 64 + slot0);                               \
    a1 = *(const v4i*)(As + (arow + 32) * 64 + slot0);                        \
    b0 = *(const v4i*)(Bs + brow * 64 + slot0);                               \
    b1 = *(const v4i*)(Bs + (brow + 32) * 64 + slot0);                        \
    if (dostage) STG(sbo, skoff, 0);                                          \
    BAR();                                                                    \
    FENCE();                                                                  \
    SETP(1);                                                                  \
    acc[0][0] = MFMA(a0, b0, acc[0][0]);                                      \
    acc[0][1] = MFMA(a0, b1, acc[0][1]);                                      \
    acc[1][0] = MFMA(a1, b0, acc[1][0]);                                      \
    acc[1][1] = MFMA(a1, b1, acc[1][1]);                                      \
    SETP(0);                                                                  \
    FENCE();                                                                  \
    BAR();                                                                    \
    {                                                                         \
      v4i b2 = *(const v4i*)(Bs + (brow + 64) * 64 + slot0);                  \
      v4i b3 = *(const v4i*)(Bs + (brow + 96) * 64 + slot0);                  \
      if (dostage) STG(sbo, skoff, 1);                                        \
      BAR();                                                                  \
      FENCE();                                                                \
      SETP(1);                                                                \
      acc[0][2] = MFMA(a0, b2, acc[0][2]);                                    \
      acc[0][3] = MFMA(a0, b3, acc[0][3]);                                    \
      acc[1][2] = MFMA(a1, b2, acc[1][2]);                                    \
      acc[1][3] = MFMA(a1, b3, acc[1][3]);                                    \
      SETP(0);                                                                \
      FENCE();                                                                \
      BAR();                                                                  \
    }                                                                         \
    a0 = *(const v4i*)(As + arow * 64 + slot1);                               \
    a1 = *(const v4i*)(As + (arow + 32) * 64 + slot1);                        \
    b0 = *(const v4i*)(Bs + brow * 64 + slot1);                               \
    b1 = *(const v4i*)(Bs + (brow + 32) * 64 + slot1);                        \
    if (dostage) STG(sbo, skoff, 2);                                          \
    BAR();                                                                    \
    FENCE();                                                                  \
    SETP(1);                                                                  \
    acc[0][0] = MFMA(a0, b0, acc[0][0]);                                      \
    acc[0][1] = MFMA(a0, b1, acc[0][1]);                                      \
    acc[1][0] = MFMA(a1, b0, acc[1][0]);                                      \
    acc[1][1] = MFMA(a1, b1, acc[1][1]);                                      \
    SETP(0);                                                                  \
    FENCE();                                                                  \
    BAR();                                                                    \
    {                                                                         \
      v4i b2 = *(const v4i*)(Bs + (brow + 64) * 64 + slot1);                  \
      v4i b3 = *(const v4i*)(Bs + (brow + 96) * 64 + slot1);                  \
      if (dostage) STG(sbo, skoff, 3);                                        \
      BAR();                                                                  \
      FENCE();                                                                \
      SETP(1);                                                                \
      acc[0][2] = MFMA(a0, b2, acc[0][2]);                                    \
      acc[0][3] = MFMA(a0, b3, acc[0][3]);                                    \
      acc[1][2] = MFMA(a1, b2, acc[1][2]);                                    \
      acc[1][3] = MFMA(a1, b3, acc[1][3]);                                    \
      SETP(0);                                                                \
      FENCE();                                                                \
      TAILWAIT;                                                               \
      BAR();                                                                  \
    }                                                                         \
  } while (0)

  STAGE(0, 0);
  STAGE(32768, 64);
  WAITV(4);
  BAR();

#pragma unroll 1
  for (int kt = 0; kt < 60; kt += 3) {
    TILE(0, 65536, (kt + 2) * 64, 1, WAITV(4));
    TILE(32768, 0, (kt + 3) * 64, 1, WAITV(4));
    TILE(65536, 32768, (kt + 4) * 64, 1, WAITV(4));
  }
  TILE(0, 65536, 62 * 64, 1, WAITV(4));  // kt=60, stages t62
  TILE(32768, 0, 63 * 64, 1, WAITV(4));  // kt=61, stages t63
  TILE(65536, 0, 0, 0, WAITV(0));        // kt=62, drain t63
  TILE(0, 0, 0, 0, (void)0);             // kt=63

  const int col = l & 31;
#pragma unroll
  for (int i = 0; i < 2; ++i) {
    const int gm0 = bm + warow * 64 + i * 32;
#pragma unroll
    for (int j = 0; j < 4; ++j) {
      const int gn = bn + wbcol * 128 + j * 32 + col;
      const int cs = 66 * csy[gn] - 8650752;  // -2112*4096
#pragma unroll
      for (int r = 0; r < 16; ++r) {
        const int row = (r & 3) + 8 * (r >> 2) + 4 * lhalf;
        const int gm = gm0 + row;
        const int val = acc[i][j][r] - 32 * rsx[gm] + cs;
        out[(size_t)gm * Ndim + gn] = 7.5e-4f * (float)val;
      }
    }
  }
#undef STAGE
#undef STG
#undef TILE
#undef MFMA
#undef SETP
#undef FENCE
#undef BAR
#undef WAITV
}

extern "C" void kernel_launch(void* const* d_in, const int* in_sizes, int n_in,
                              void* d_out, int out_size, void* d_ws, size_t ws_size,
                              hipStream_t stream) {
  (void)in_sizes; (void)n_in; (void)out_size; (void)ws_size;
  const int* x = (const int*)d_in[0];
  const int* y = (const int*)d_in[1];
  float* out = (float*)d_out;
  char* ws = (char*)d_ws;
  char* x8 = ws;                                          // 16 MB
  char* yt = ws + (size_t)Mdim * Kdim;                    // 16 MB (row-major)
  int* rsx = (int*)(ws + (size_t)Mdim * Kdim + (size_t)Kdim * Ndim);
  int* csy = rsx + Mdim;

  // 2 dispatches total (memset eliminated; csy written directly by y-blocks).
  pack_fused_kernel<<<256 + Mdim / 2, 512, 0, stream>>>(x, y, x8, yt, rsx, csy);
  gemm_i8_kernel<<<dim3(Ndim / 256, Mdim / 256), 512, 0, stream>>>(x8, yt, rsx,
                                                                   csy, out);
}